// Round 10
// baseline (416.533 us; speedup 1.0000x reference)
//
#include <hip/hip_runtime.h>

// apply_cdna_kernels: out[n,b,c,h,w] = sum_{kh,kw} images[b,h+kh-2,w+kw-2,c] * kernels[b,kh,kw,n]
// images: [64,128,128,3] f32   kernels: [64,5,5,10] f32   out: [10,64,3,128,128] f32
//
// R11: occupancy/overlap fix. R10 (clean counters: no spill, WRITE==output,
// FETCH 50MB) ran 90us at Occupancy 29% — ~2.3 resident blocks/CU, nothing to
// hide each block's serial {stage -> barrier -> compute} chain under. All
// low-residency rounds pin at 70-90us with VALU/HBM/LDS all <30%.
//  - tile 8h x 64w, 128 threads (2 waves), LDS 9.8KB
//  - grid = 16ht x 2wt x 64b = 2048 blocks = 8 resident/CU (LDS limit 16,
//    wave limit 8 at launch_bounds(128,4) -> VGPR<=128, live ~70)
//  - 8 independent blocks/CU: stage latency + barriers of one overlap
//    seven others' FMA streams
//  - per-thread micro-kernel = R8's proven best: 1h x 4w x 3c, 5 n-pairs
//    (LDS reads halved), 30x ds_read_b128/pair, plain uniform weight loads
//    (s_load path, R9/R10 SGPR=112 confirms), plain dwordx4 stores
// Floors: write+read 23us || VALU 10-20us || LDS 9us -> predict 30-45us.

#define B_  64
#define H_  128
#define W_  128
#define C_  3
#define N_  10
#define KH_ 5
#define KW_ 5
#define TH_ 8                  // tile height
#define TW_ 64                 // tile width
#define LDS_ROWS (TH_ + 4)     // 12 rows incl. halo
#define ROW_PX  (TW_ + 4)      // 68 px per row
#define ROW_F   (ROW_PX * C_)  // 204 floats per row (816B, 16B-aligned)
#define ROW_F4  (ROW_F / 4)    // 51 float4 per row
#define ROW_VALID (W_ * C_)    // 384 valid floats per global image row
#define HW_ (H_ * W_)          // 16384

__global__ __launch_bounds__(128, 4) void cdna_apply_kernel(
    const float* __restrict__ images,
    const float* __restrict__ kernels,
    float* __restrict__ out)
{
    __shared__ __align__(16) float s_img[LDS_ROWS * ROW_F];

    const int tid = threadIdx.x;
    const int t   = blockIdx.x;   // 32 tiles: ht*2 + wtile
    const int b   = blockIdx.y;   // 64
    const int ht  = t >> 1;
    const int wt  = t & 1;
    const int y0  = ht * TH_;
    const int x0f = wt * (TW_ * C_);   // tile start as float offset in global row

    // ---- stage image tile (12 rows x 51 float4; zero-padded halo), once ----
    const float* __restrict__ ib = images + (long)b * (H_ * W_ * C_);
    for (int i = tid; i < LDS_ROWS * ROW_F4; i += 128) {
        const int r  = i / ROW_F4;             // LDS row 0..11
        const int q  = i - r * ROW_F4;         // float4 index in row, 0..50
        const int y  = y0 + r - 2;
        float v0 = 0.f, v1 = 0.f, v2 = 0.f, v3 = 0.f;
        if ((unsigned)y < (unsigned)H_) {
            const float* grow = ib + (long)y * ROW_VALID;
            const int f0 = x0f + q * 4 - 6;    // float offset in global row (even)
            if (f0 >= 0 && f0 <= ROW_VALID - 4) {
                const float2 a  = *(const float2*)(grow + f0);
                const float2 c2 = *(const float2*)(grow + f0 + 2);
                v0 = a.x; v1 = a.y; v2 = c2.x; v3 = c2.y;
            } else {
                if (f0 + 0 >= 0 && f0 + 0 < ROW_VALID) v0 = grow[f0 + 0];
                if (f0 + 1 >= 0 && f0 + 1 < ROW_VALID) v1 = grow[f0 + 1];
                if (f0 + 2 >= 0 && f0 + 2 < ROW_VALID) v2 = grow[f0 + 2];
                if (f0 + 3 >= 0 && f0 + 3 < ROW_VALID) v3 = grow[f0 + 3];
            }
        }
        *(float4*)(&s_img[r * ROW_F + q * 4]) = make_float4(v0, v1, v2, v3);
    }
    __syncthreads();

    const int tx = tid & 15;      // col group: cols x0 + 4tx .. +3
    const int ty = tid >> 4;      // 0..7 output row within tile

    const float* __restrict__ kb = kernels + (long)b * (KH_ * KW_ * N_);
    const int h = y0 + ty;
    float* ob0 = out + (long)b * (C_ * HW_) + (long)h * W_ + wt * TW_ + tx * 4;
    const long nstride = (long)B_ * C_ * HW_;

    #pragma unroll 1
    for (int np = 0; np < N_ / 2; ++np) {
        const int n0 = 2 * np;
        // 2 x 25 block-uniform weights: uniform address -> s_load path
        float wt0[KH_ * KW_], wt1[KH_ * KW_];
        #pragma unroll
        for (int k = 0; k < KH_ * KW_; ++k) {
            wt0[k] = kb[k * N_ + n0];
            wt1[k] = kb[k * N_ + n0 + 1];
        }

        float a0[12], a1[12];                  // [c*4 + w] for n0, n0+1
        #pragma unroll
        for (int i = 0; i < 12; ++i) { a0[i] = 0.f; a1[i] = 0.f; }

        #pragma unroll
        for (int r = 0; r < KH_; ++r) {
            const float4* rp = (const float4*)&s_img[(ty + r) * ROW_F + tx * 12];
            float px[24];                      // pixels x=4tx-2..4tx+5, 3 c each
            #pragma unroll
            for (int j = 0; j < 6; ++j) {      // 6x ds_read_b128
                const float4 v = rp[j];
                px[j * 4 + 0] = v.x; px[j * 4 + 1] = v.y;
                px[j * 4 + 2] = v.z; px[j * 4 + 3] = v.w;
            }
            #pragma unroll
            for (int kw = 0; kw < KW_; ++kw) {
                const float w0 = wt0[r * KW_ + kw];
                const float w1 = wt1[r * KW_ + kw];
                #pragma unroll
                for (int w = 0; w < 4; ++w)
                    #pragma unroll
                    for (int c = 0; c < C_; ++c) {
                        const float p = px[(kw + w) * 3 + c];
                        a0[c * 4 + w] = fmaf(p, w0, a0[c * 4 + w]);
                        a1[c * 4 + w] = fmaf(p, w1, a1[c * 4 + w]);
                    }
            }
        }

        // plain dwordx4 stores: 256B contiguous per 16-lane row group, sector-complete
        float* p0 = ob0 + (long)n0 * nstride;
        float* p1 = p0 + nstride;
        #pragma unroll
        for (int c = 0; c < C_; ++c) {
            *(float4*)(p0 + (long)c * HW_) = make_float4(a0[c*4+0], a0[c*4+1], a0[c*4+2], a0[c*4+3]);
            *(float4*)(p1 + (long)c * HW_) = make_float4(a1[c*4+0], a1[c*4+1], a1[c*4+2], a1[c*4+3]);
        }
    }
}

extern "C" void kernel_launch(void* const* d_in, const int* in_sizes, int n_in,
                              void* d_out, int out_size, void* d_ws, size_t ws_size,
                              hipStream_t stream) {
    const float* images  = (const float*)d_in[0];
    const float* kernels = (const float*)d_in[1];
    float* out = (float*)d_out;

    dim3 grid((H_ / TH_) * (W_ / TW_), B_);   // 32 x 64 = 2048 blocks, 8/CU
    cdna_apply_kernel<<<grid, 128, 0, stream>>>(images, kernels, out);
}

// Round 11
// 153.337 us; speedup vs baseline: 2.7165x; 2.7165x over previous
//
#include <hip/hip_runtime.h>

// apply_cdna_kernels: out[n,b,c,h,w] = sum_{kh,kw} images[b,h+kh-2,w+kw-2,c] * kernels[b,kh,kw,n]
// images: [64,128,128,3] f32   kernels: [64,5,5,10] f32   out: [10,64,3,128,128] f32
//
// R12 = R8 (best: kernel ~45-50us by cross-round subtraction) + residency fix.
// Allocator law (5 rounds): VGPR budget = 256/launch_bounds_arg. R8's
// VGPR==128 came from readfirstlane forcing 50 weight loads through vector
// regs; R9/R10 proved plain uniform-address loads use the scalar (s_load)
// path: SGPR=112, VGPR=68.
//  - drop readfirstlane -> vector live ~70-85 VGPR -> 6 waves/SIMD = 24/CU
//  - split n-range: block does 5 n (2 pairs + 1 singleton), grid z=2 ->
//    2048 blocks = 8 queued/CU, residency min(LDS 8, VGPR 6) = 6 blocks/CU
//    (R8 was grid+VGPR-capped at 4 blocks/16 waves)
//  - keep: TH=8 full-W tile staged once, ds_read_b128 px reads, plain
//    dwordx4 stores (sector-complete), launch_bounds(256,2), unroll-1 n loop
// Floors: write+read ~23us || VALU ~12us || LDS ~11us -> predict 28-40us.

#define B_  64
#define H_  128
#define W_  128
#define C_  3
#define N_  10
#define KH_ 5
#define KW_ 5
#define TH_ 8                  // tile height (full W width)
#define LDS_ROWS (TH_ + 4)     // 12 rows incl. halo
#define ROW_F ((W_ + 4) * C_)  // 132 px * 3 = 396 floats per row (1584B)
#define ROW_VALID (W_ * C_)    // 384 valid floats per global image row
#define HW_ (H_ * W_)          // 16384

__global__ __launch_bounds__(256, 2) void cdna_apply_kernel(
    const float* __restrict__ images,
    const float* __restrict__ kernels,
    float* __restrict__ out)
{
    __shared__ __align__(16) float s_img[LDS_ROWS * ROW_F];

    const int tid = threadIdx.x;
    const int ht  = blockIdx.x;   // 16
    const int b   = blockIdx.y;   // 64
    const int g   = blockIdx.z;   // 2: n-group, n in [5g, 5g+5)
    const int y0  = ht * TH_;

    // ---- stage image tile (12 rows x 99 float4; zero-padded halo), once ----
    const float* __restrict__ ib = images + (long)b * (H_ * W_ * C_);
    for (int i = tid; i < LDS_ROWS * (ROW_F / 4); i += 256) {
        const int r  = i / (ROW_F / 4);        // LDS row 0..11
        const int q  = i - r * (ROW_F / 4);    // float4 index in row, 0..98
        const int y  = y0 + r - 2;
        float v0 = 0.f, v1 = 0.f, v2 = 0.f, v3 = 0.f;
        if ((unsigned)y < (unsigned)H_) {
            const float* grow = ib + (long)y * ROW_VALID;
            const int f0 = q * 4 - 6;          // offset into 384-float global row (even)
            if (f0 >= 0 && f0 <= ROW_VALID - 4) {
                const float2 a  = *(const float2*)(grow + f0);
                const float2 c2 = *(const float2*)(grow + f0 + 2);
                v0 = a.x; v1 = a.y; v2 = c2.x; v3 = c2.y;
            } else {
                if (f0 + 0 >= 0 && f0 + 0 < ROW_VALID) v0 = grow[f0 + 0];
                if (f0 + 1 >= 0 && f0 + 1 < ROW_VALID) v1 = grow[f0 + 1];
                if (f0 + 2 >= 0 && f0 + 2 < ROW_VALID) v2 = grow[f0 + 2];
                if (f0 + 3 >= 0 && f0 + 3 < ROW_VALID) v3 = grow[f0 + 3];
            }
        }
        *(float4*)(&s_img[r * ROW_F + q * 4]) = make_float4(v0, v1, v2, v3);
    }
    __syncthreads();

    const int tx = tid & 31;      // cols 4tx..4tx+3
    const int ty = tid >> 5;      // 0..7 output row within tile

    const float* __restrict__ kb = kernels + (long)b * (KH_ * KW_ * N_);
    const int h = y0 + ty;
    float* ob0 = out + (long)b * (C_ * HW_) + (long)h * W_ + tx * 4;
    const long nstride = (long)B_ * C_ * HW_;
    const int nbase = 5 * g;

    // ---- two n-pairs ----
    #pragma unroll 1
    for (int np = 0; np < 2; ++np) {
        const int n0 = nbase + 2 * np;
        // 2 x 25 block-uniform weights: uniform address -> s_load path (no readfirstlane)
        float wt0[KH_ * KW_], wt1[KH_ * KW_];
        #pragma unroll
        for (int k = 0; k < KH_ * KW_; ++k) {
            wt0[k] = kb[k * N_ + n0];
            wt1[k] = kb[k * N_ + n0 + 1];
        }

        float a0[12], a1[12];                  // [c*4 + w] for n0, n0+1
        #pragma unroll
        for (int i = 0; i < 12; ++i) { a0[i] = 0.f; a1[i] = 0.f; }

        #pragma unroll
        for (int r = 0; r < KH_; ++r) {
            const float4* rp = (const float4*)&s_img[(ty + r) * ROW_F + tx * 12];
            float px[24];                      // pixels x=4tx-2..4tx+5, 3 c each
            #pragma unroll
            for (int j = 0; j < 6; ++j) {      // 6x ds_read_b128, conflict-free
                const float4 t = rp[j];
                px[j * 4 + 0] = t.x; px[j * 4 + 1] = t.y;
                px[j * 4 + 2] = t.z; px[j * 4 + 3] = t.w;
            }
            #pragma unroll
            for (int kw = 0; kw < KW_; ++kw) {
                const float w0 = wt0[r * KW_ + kw];
                const float w1 = wt1[r * KW_ + kw];
                #pragma unroll
                for (int w = 0; w < 4; ++w)
                    #pragma unroll
                    for (int c = 0; c < C_; ++c) {
                        const float p = px[(kw + w) * 3 + c];
                        a0[c * 4 + w] = fmaf(p, w0, a0[c * 4 + w]);
                        a1[c * 4 + w] = fmaf(p, w1, a1[c * 4 + w]);
                    }
            }
        }

        float* p0 = ob0 + (long)n0 * nstride;
        float* p1 = p0 + nstride;
        #pragma unroll
        for (int c = 0; c < C_; ++c) {
            *(float4*)(p0 + (long)c * HW_) = make_float4(a0[c*4+0], a0[c*4+1], a0[c*4+2], a0[c*4+3]);
            *(float4*)(p1 + (long)c * HW_) = make_float4(a1[c*4+0], a1[c*4+1], a1[c*4+2], a1[c*4+3]);
        }
    }

    // ---- singleton n = nbase + 4 ----
    {
        const int n4 = nbase + 4;
        float wt4[KH_ * KW_];
        #pragma unroll
        for (int k = 0; k < KH_ * KW_; ++k)
            wt4[k] = kb[k * N_ + n4];

        float a4[12];
        #pragma unroll
        for (int i = 0; i < 12; ++i) a4[i] = 0.f;

        #pragma unroll
        for (int r = 0; r < KH_; ++r) {
            const float4* rp = (const float4*)&s_img[(ty + r) * ROW_F + tx * 12];
            float px[24];
            #pragma unroll
            for (int j = 0; j < 6; ++j) {
                const float4 t = rp[j];
                px[j * 4 + 0] = t.x; px[j * 4 + 1] = t.y;
                px[j * 4 + 2] = t.z; px[j * 4 + 3] = t.w;
            }
            #pragma unroll
            for (int kw = 0; kw < KW_; ++kw) {
                const float wgt = wt4[r * KW_ + kw];
                #pragma unroll
                for (int w = 0; w < 4; ++w)
                    #pragma unroll
                    for (int c = 0; c < C_; ++c)
                        a4[c * 4 + w] = fmaf(px[(kw + w) * 3 + c], wgt, a4[c * 4 + w]);
            }
        }

        float* p4 = ob0 + (long)n4 * nstride;
        #pragma unroll
        for (int c = 0; c < C_; ++c)
            *(float4*)(p4 + (long)c * HW_) =
                make_float4(a4[c*4+0], a4[c*4+1], a4[c*4+2], a4[c*4+3]);
    }
}

extern "C" void kernel_launch(void* const* d_in, const int* in_sizes, int n_in,
                              void* d_out, int out_size, void* d_ws, size_t ws_size,
                              hipStream_t stream) {
    const float* images  = (const float*)d_in[0];
    const float* kernels = (const float*)d_in[1];
    float* out = (float*)d_out;

    dim3 grid(H_ / TH_, B_, 2);   // 16 x 64 x 2 = 2048 blocks, ~6 resident/CU
    cdna_apply_kernel<<<grid, 256, 0, stream>>>(images, kernels, out);
}

// Round 12
// 143.396 us; speedup vs baseline: 2.9048x; 1.0693x over previous
//
#include <hip/hip_runtime.h>

// apply_cdna_kernels: out[n,b,c,h,w] = sum_{kh,kw} images[b,h+kh-2,w+kw-2,c] * kernels[b,kh,kw,n]
// images: [64,128,128,3] f32   kernels: [64,5,5,10] f32   out: [10,64,3,128,128] f32
//
// R13: real occupancy fix. R12 kept bounds(256,2)=128-VGPR budget -> compiler
// filled it -> still 4 waves/SIMD; added overhead, no lever. Allocator law
// (6 pts): budget = 256/arg; compiler fills budget.
//  - bounds(256,3) = 84 budget; live set engineered ~65: weights loaded
//    PER-ROW inside an unroll-1 r-loop (10 s_loads live, not 50), px 24,
//    acc 24 -> VGPR<=84 -> 6 waves/SIMD = 24 waves/CU (1.5x R8)
//  - TH=4 full-W tile -> 2048 blocks (8 queued/CU, 6 resident by VGPR)
//  - 256 thr = 32tx x 4ty x 2 n-halves: half0 pairs (01)(23)(45), half1
//    (67)(89) -> 0.5 LDS-passes/n, no singleton; s readfirstlane'd so
//    weight addrs stay scalar (s_load path, proven R9/R10)
//  - wave = 32tx x 2ty lane geometry: the only pattern that ever measured
//    SQ_LDS_BANK_CONFLICT=0 (R1/R4/R10); R11's 16tx showed 491K
//  - keep: ds_read_b128 px (16B-aligned via halo-inclusive rows), plain
//    dwordx4 stores (sector-complete 512B segments), stage-once
// Floors: write+read ~23us || VALU ~12us || LDS ~9us -> predict 28-40us.

#define B_  64
#define H_  128
#define W_  128
#define C_  3
#define N_  10
#define KH_ 5
#define KW_ 5
#define TH_ 4                  // tile height (full W width)
#define LDS_ROWS (TH_ + 4)     // 8 rows incl. halo
#define ROW_F ((W_ + 4) * C_)  // 132 px * 3 = 396 floats per row (1584B)
#define ROW_VALID (W_ * C_)    // 384 valid floats per global image row
#define HW_ (H_ * W_)          // 16384

__global__ __launch_bounds__(256, 3) void cdna_apply_kernel(
    const float* __restrict__ images,
    const float* __restrict__ kernels,
    float* __restrict__ out)
{
    __shared__ __align__(16) float s_img[LDS_ROWS * ROW_F];

    const int tid = threadIdx.x;
    const int ht  = blockIdx.x;   // 32
    const int b   = blockIdx.y;   // 64
    const int y0  = ht * TH_;

    // ---- stage image tile (8 rows x 99 float4; zero-padded halo), once ----
    const float* __restrict__ ib = images + (long)b * (H_ * W_ * C_);
    for (int i = tid; i < LDS_ROWS * (ROW_F / 4); i += 256) {
        const int r  = i / (ROW_F / 4);        // LDS row 0..7
        const int q  = i - r * (ROW_F / 4);    // float4 index in row, 0..98
        const int y  = y0 + r - 2;
        float v0 = 0.f, v1 = 0.f, v2 = 0.f, v3 = 0.f;
        if ((unsigned)y < (unsigned)H_) {
            const float* grow = ib + (long)y * ROW_VALID;
            const int f0 = q * 4 - 6;          // offset into 384-float global row (even)
            if (f0 >= 0 && f0 <= ROW_VALID - 4) {
                const float2 a  = *(const float2*)(grow + f0);
                const float2 c2 = *(const float2*)(grow + f0 + 2);
                v0 = a.x; v1 = a.y; v2 = c2.x; v3 = c2.y;
            } else {
                if (f0 + 0 >= 0 && f0 + 0 < ROW_VALID) v0 = grow[f0 + 0];
                if (f0 + 1 >= 0 && f0 + 1 < ROW_VALID) v1 = grow[f0 + 1];
                if (f0 + 2 >= 0 && f0 + 2 < ROW_VALID) v2 = grow[f0 + 2];
                if (f0 + 3 >= 0 && f0 + 3 < ROW_VALID) v3 = grow[f0 + 3];
            }
        }
        *(float4*)(&s_img[r * ROW_F + q * 4]) = make_float4(v0, v1, v2, v3);
    }
    __syncthreads();

    const int tx = tid & 31;               // cols 4tx..4tx+3
    const int ty = (tid >> 5) & 3;         // 0..3 output row within tile
    // n-half: wave-uniform; force scalar so weight addresses take s_load path
    const int s  = __builtin_amdgcn_readfirstlane(tid >> 7);

    const float* __restrict__ kb = kernels + (long)b * (KH_ * KW_ * N_);
    const int h = y0 + ty;
    float* ob0 = out + (long)b * (C_ * HW_) + (long)h * W_ + tx * 4;
    const long nstride = (long)B_ * C_ * HW_;

    const int pmax = 3 - s;                // half0: 3 pairs (n 0-5), half1: 2 pairs (n 6-9)

    #pragma unroll 1
    for (int p = 0; p < pmax; ++p) {
        const int n0 = 2 * p + 6 * s;

        float a0[12], a1[12];              // [c*4 + w] for n0, n0+1
        #pragma unroll
        for (int i = 0; i < 12; ++i) { a0[i] = 0.f; a1[i] = 0.f; }

        // unroll-1 r-loop: only one row's weights (10 SGPRs) + px (24 VGPR) live
        #pragma unroll 1
        for (int r = 0; r < KH_; ++r) {
            float w0[KW_], w1[KW_];        // uniform addresses -> s_load
            #pragma unroll
            for (int kw = 0; kw < KW_; ++kw) {
                w0[kw] = kb[(r * KW_ + kw) * N_ + n0];
                w1[kw] = kb[(r * KW_ + kw) * N_ + n0 + 1];
            }

            const float4* rp = (const float4*)&s_img[(ty + r) * ROW_F + tx * 12];
            float px[24];                  // pixels x=4tx-2..4tx+5, 3 c each
            #pragma unroll
            for (int j = 0; j < 6; ++j) {  // 6x ds_read_b128, conflict-free
                const float4 t = rp[j];
                px[j * 4 + 0] = t.x; px[j * 4 + 1] = t.y;
                px[j * 4 + 2] = t.z; px[j * 4 + 3] = t.w;
            }

            #pragma unroll
            for (int kw = 0; kw < KW_; ++kw) {
                const float g0 = w0[kw];
                const float g1 = w1[kw];
                #pragma unroll
                for (int w = 0; w < 4; ++w)
                    #pragma unroll
                    for (int c = 0; c < C_; ++c) {
                        const float pv = px[(kw + w) * 3 + c];
                        a0[c * 4 + w] = fmaf(pv, g0, a0[c * 4 + w]);
                        a1[c * 4 + w] = fmaf(pv, g1, a1[c * 4 + w]);
                    }
            }
        }

        // plain dwordx4 stores: 512B contiguous per (n,c,row) across 32 lanes
        float* p0 = ob0 + (long)n0 * nstride;
        float* p1 = p0 + nstride;
        #pragma unroll
        for (int c = 0; c < C_; ++c) {
            *(float4*)(p0 + (long)c * HW_) = make_float4(a0[c*4+0], a0[c*4+1], a0[c*4+2], a0[c*4+3]);
            *(float4*)(p1 + (long)c * HW_) = make_float4(a1[c*4+0], a1[c*4+1], a1[c*4+2], a1[c*4+3]);
        }
    }
}

extern "C" void kernel_launch(void* const* d_in, const int* in_sizes, int n_in,
                              void* d_out, int out_size, void* d_ws, size_t ws_size,
                              hipStream_t stream) {
    const float* images  = (const float*)d_in[0];
    const float* kernels = (const float*)d_in[1];
    float* out = (float*)d_out;

    dim3 grid(H_ / TH_, B_);   // 32 x 64 = 2048 blocks, ~6 resident/CU
    cdna_apply_kernel<<<grid, 256, 0, stream>>>(images, kernels, out);
}